// Round 12
// baseline (175.085 us; speedup 1.0000x reference)
//
#include <hip/hip_runtime.h>
#include <math.h>

// Problem constants (from reference)
#define NN 10000
#define INF 512
#define HF  512
#define OF  64
#define NE  163840
#define MAXDEG 64   // P(Poisson(16.4) >= 64) ~ 7e-18/node: ELL-64 is statistically exact

typedef __attribute__((ext_vector_type(8))) short bf16x8_t;   // 8 bf16 = 4 VGPRs
typedef __attribute__((ext_vector_type(4))) float f32x4_t;    // 4 fp32 acc

__device__ inline ushort f2bf(float f) {
    unsigned u = __float_as_uint(f);
    u = (u + 0x7FFF + ((u >> 16) & 1)) >> 16;   // RNE
    return (ushort)u;
}
__device__ inline float bf2f(ushort u) {
    return __uint_as_float(((unsigned)u) << 16);
}

// global -> LDS direct DMA, 16 B/lane. LDS dest = wave-uniform base + lane*16.
#define GLL(gp, lp) __builtin_amdgcn_global_load_lds(                         \
    (const __attribute__((address_space(1))) unsigned int*)(gp),              \
    (__attribute__((address_space(3))) unsigned int*)(lp), 16, 0, 0)

// ---------------- D1: conversions + gdeg zero + h2f zero (grid-partitioned) --------
// blocks [0,2500): x fp32->bf16; [2500,2756): W1T; [2756,2788): W2T;
// [2788,2828): gdeg zero; [2828,3453): h2f zero (625*256 float4 = 640000 floats).
#define CCB_X  2500
#define CCB_W1 2756
#define CCB_W2 2788
#define CCB_Z  2828
#define CCB_H2 3453
__global__ __launch_bounds__(256) void k_cvt(const float* __restrict__ X,
                                             ushort* __restrict__ Xb,
                                             const float* __restrict__ W1,
                                             ushort* __restrict__ W1T,
                                             const float* __restrict__ W2,
                                             ushort* __restrict__ W2T,
                                             int* __restrict__ gdeg,
                                             float* __restrict__ h2f) {
    __shared__ float tl[32][33];
    int b = blockIdx.x, t = threadIdx.x;
    if (b < CCB_X) {
        int i = (b * 256 + t) * 2;
        const float4* Xv = (const float4*)X;
        float4 v0 = Xv[i], v1 = Xv[i + 1];
        ushort4 o0, o1;
        o0.x = f2bf(v0.x); o0.y = f2bf(v0.y); o0.z = f2bf(v0.z); o0.w = f2bf(v0.w);
        o1.x = f2bf(v1.x); o1.y = f2bf(v1.y); o1.z = f2bf(v1.z); o1.w = f2bf(v1.w);
        ((ushort4*)Xb)[i] = o0;
        ((ushort4*)Xb)[i + 1] = o1;
    } else if (b < CCB_W2) {
        const float* W; ushort* WT; int N, tile;
        if (b < CCB_W1) { W = W1; WT = W1T; N = 512; tile = b - CCB_X; }
        else            { W = W2; WT = W2T; N = 64;  tile = b - CCB_W1; }
        int k0 = (tile & 15) * 32;
        int n0 = (tile >> 4) * 32;
        int tx = t & 31, ty = t >> 5;
#pragma unroll
        for (int i = 0; i < 4; i++)
            tl[ty + i * 8][tx] = W[(size_t)(k0 + ty + i * 8) * N + n0 + tx];
        __syncthreads();
#pragma unroll
        for (int i = 0; i < 4; i++)
            WT[(size_t)(n0 + ty + i * 8) * 512 + k0 + tx] = f2bf(tl[tx][ty + i * 8]);
    } else if (b < CCB_Z) {
        int i = (b - CCB_W2) * 256 + t;
        if (i < NN) gdeg[i] = 0;
    } else {
        int i = (b - CCB_Z) * 256 + t;               // < 160000 by construction
        ((float4*)h2f)[i] = make_float4(0.f, 0.f, 0.f, 0.f);
    }
}

// ---------------- D2: MFMA GEMM1 (128x128, global_load_lds + XOR swizzle) + ELL ----
#define GEMM_B 316
__global__ __launch_bounds__(256) void k_gemm_ell(const ushort* __restrict__ Xb,
                                                  const ushort* __restrict__ WT,
                                                  ushort* __restrict__ Y,
                                                  const int* __restrict__ src,
                                                  const int* __restrict__ dst,
                                                  int* __restrict__ gdeg,
                                                  int* __restrict__ ell, int E) {
    __shared__ ushort As[128 * 64];   // 16 KB
    __shared__ ushort Bs[128 * 64];   // 16 KB
    int b = blockIdx.x;
    int tid = threadIdx.x;
    if (b >= GEMM_B) {
        int e = (b - GEMM_B) * 256 + tid;
        if (e < E) {
            int s = src[e], d = dst[e];
            int r = atomicAdd(&gdeg[d], 1);
            if (r < MAXDEG) ell[d * MAXDEG + r] = s;
        }
        return;
    }
    int lane = tid & 63;
    int wave = tid >> 6;
    int m = lane & 15;
    int q = lane >> 4;
    int m7 = m & 7;
    int wr = wave >> 1;
    int wc = wave & 1;
    int row0 = (b % 79) * 128;
    int col0 = (b / 79) * 128;

    int lrow = lane >> 3;
    int lg = ((lane & 7) ^ lrow) * 8;

    f32x4_t acc[4][4];
#pragma unroll
    for (int r = 0; r < 4; r++)
#pragma unroll
        for (int c = 0; c < 4; c++) acc[r][c] = (f32x4_t){0.f, 0.f, 0.f, 0.f};

    const ushort* gA0 = Xb + (size_t)(row0 + wave * 32 + lrow) * 512 + lg;
    const ushort* gB0 = WT + (size_t)(col0 + wave * 32 + lrow) * 512 + lg;
    ushort* lA0 = As + (wave * 32) * 64;
    ushort* lB0 = Bs + (wave * 32) * 64;

    for (int kb = 0; kb < 512; kb += 64) {
#pragma unroll
        for (int j = 0; j < 4; j++) {
            GLL(gA0 + kb + j * 8 * 512, lA0 + j * 8 * 64);
            GLL(gB0 + kb + j * 8 * 512, lB0 + j * 8 * 64);
        }
        __syncthreads();
#pragma unroll
        for (int kc = 0; kc < 2; kc++) {
            bf16x8_t a[4], bb[4];
            int slot = ((kc * 4 + q) ^ m7) * 8;
#pragma unroll
            for (int r = 0; r < 4; r++)
                a[r] = *(const bf16x8_t*)(As + (wr * 64 + r * 16 + m) * 64 + slot);
#pragma unroll
            for (int c = 0; c < 4; c++)
                bb[c] = *(const bf16x8_t*)(Bs + (wc * 64 + c * 16 + m) * 64 + slot);
#pragma unroll
            for (int r = 0; r < 4; r++)
#pragma unroll
                for (int c = 0; c < 4; c++)
                    acc[r][c] = __builtin_amdgcn_mfma_f32_16x16x32_bf16(a[r], bb[c], acc[r][c], 0, 0, 0);
        }
        __syncthreads();
    }
#pragma unroll
    for (int r = 0; r < 4; r++) {
#pragma unroll
        for (int c = 0; c < 4; c++) {
#pragma unroll
            for (int reg = 0; reg < 4; reg++) {
                int row = row0 + wr * 64 + r * 16 + q * 4 + reg;
                int col = col0 + wc * 64 + c * 16 + m;
                if (row < NN) Y[(size_t)row * 512 + col] = f2bf(acc[r][c][reg]);
            }
        }
    }
}

// ---------------- D3: FUSED agg1 + partial GEMM2 (aggregation is linear) -----------
// Block (nt, slice): aggregate slice (128 feats) for 128 nodes into LDS bf16 tile
// (gathers stay XCD-sliced: 2.56 MB/slice working set, L2-resident), then MFMA
// a1s[128x128] @ w2s[64x128] and atomicAdd fp32 partials into h2f. Kills the
// gemm64 dispatch + a1b round-trip. Neighbor (src,w) broadcast via __shfl.
#define FUSE_B 316   // 79 node-tiles x 4 slices
#define LDA2 136     // row stride: 16B-aligned, 4-bank rotation per row
__global__ __launch_bounds__(256) void k_fuse(const ushort* __restrict__ h1b,
                                              const int* __restrict__ gdeg,
                                              const int* __restrict__ ell,
                                              const float* __restrict__ b1,
                                              const ushort* __restrict__ W2T,
                                              float* __restrict__ h2f) {
    __shared__ ushort a1s[128 * LDA2];  // 34.8 KB
    __shared__ ushort w2s[64 * LDA2];   // 17.4 KB
    int bid = blockIdx.x;
    int slice = bid & 3;
    int nt = bid >> 2;
    int tid = threadIdx.x;
    int lane = tid & 63;
    int wv = tid >> 6;

    // stage W2T k-slice: thread t -> row = t>>2 (0..63), k-quarter = (t&3)*32
    {
        int row = tid >> 2, kq = (tid & 3) * 32;
        const ushort* gsrc = W2T + (size_t)row * 512 + slice * 128 + kq;
#pragma unroll
        for (int j = 0; j < 4; j++)
            *(bf16x8_t*)(w2s + row * LDA2 + kq + j * 8) = *(const bf16x8_t*)(gsrc + j * 8);
    }

    // aggregation: wave wv covers nodes nt*128 + wv*32 + [0,32); lane holds 2 feats
    int fb = slice * 128 + lane * 2;
    for (int i = 0; i < 32; i++) {
        int n = nt * 128 + wv * 32 + i;
        int nloc = wv * 32 + i;
        float ax[8], ay[8];
#pragma unroll
        for (int k = 0; k < 8; k++) { ax[k] = 0.f; ay[k] = 0.f; }
        int deg = 0;
        int sreg = 0; float wreg = 0.f;
        if (n < NN) {
            int dt = gdeg[n];
            deg = dt > MAXDEG ? MAXDEG : dt;
            float dvn = rsqrtf((float)(dt + 1));
            if (lane < deg) {
                sreg = ell[n * MAXDEG + lane];
                wreg = rsqrtf((float)(gdeg[sreg] + 1)) * dvn;
            }
            ushort2 u = *(const ushort2*)(h1b + (size_t)n * 512 + fb);
            ax[0] = bf2f(u.x) * dvn * dvn;
            ay[0] = bf2f(u.y) * dvn * dvn;
        }
        int nr = (deg + 7) & ~7;
        for (int j = 0; j < nr; j += 8) {
            int sK[8]; float wK[8];
#pragma unroll
            for (int k = 0; k < 8; k++) {
                sK[k] = __shfl(sreg, j + k, 64);
                wK[k] = __shfl(wreg, j + k, 64);
            }
#pragma unroll
            for (int k = 0; k < 8; k++) {
                ushort2 u = *(const ushort2*)(h1b + (size_t)sK[k] * 512 + fb);
                ax[k] += bf2f(u.x) * wK[k];
                ay[k] += bf2f(u.y) * wK[k];
            }
        }
        float tx = ((ax[0] + ax[1]) + (ax[2] + ax[3])) + ((ax[4] + ax[5]) + (ax[6] + ax[7]));
        float ty = ((ay[0] + ay[1]) + (ay[2] + ay[3])) + ((ay[4] + ay[5]) + (ay[6] + ay[7]));
        tx += b1[fb];
        ty += b1[fb + 1];
        ushort2 o;
        o.x = f2bf(tx > 0.f ? tx : 0.f);
        o.y = f2bf(ty > 0.f ? ty : 0.f);
        *(ushort2*)(a1s + nloc * LDA2 + lane * 2) = o;
    }
    __syncthreads();

    // partial GEMM: wave wv -> rows [wv*32, +32) x 64 cols, K = 128 (this slice)
    int m = lane & 15, q = lane >> 4;
    f32x4_t acc[2][4];
#pragma unroll
    for (int r = 0; r < 2; r++)
#pragma unroll
        for (int c = 0; c < 4; c++) acc[r][c] = (f32x4_t){0.f, 0.f, 0.f, 0.f};
#pragma unroll
    for (int kk = 0; kk < 4; kk++) {
        int ko = kk * 32 + q * 8;
        bf16x8_t a[2], bb[4];
#pragma unroll
        for (int r = 0; r < 2; r++)
            a[r] = *(const bf16x8_t*)(a1s + (wv * 32 + r * 16 + m) * LDA2 + ko);
#pragma unroll
        for (int c = 0; c < 4; c++)
            bb[c] = *(const bf16x8_t*)(w2s + (c * 16 + m) * LDA2 + ko);
#pragma unroll
        for (int r = 0; r < 2; r++)
#pragma unroll
            for (int c = 0; c < 4; c++)
                acc[r][c] = __builtin_amdgcn_mfma_f32_16x16x32_bf16(a[r], bb[c], acc[r][c], 0, 0, 0);
    }
#pragma unroll
    for (int r = 0; r < 2; r++) {
#pragma unroll
        for (int c = 0; c < 4; c++) {
#pragma unroll
            for (int reg = 0; reg < 4; reg++) {
                int row = nt * 128 + wv * 32 + r * 16 + q * 4 + reg;
                int col = c * 16 + m;
                if (row < NN) atomicAdd(&h2f[(size_t)row * 64 + col], acc[r][c][reg]);
            }
        }
    }
}

// ---------------- D4: aggregate layer 2 (fp32 h2f) + bias + log_softmax -------------
__global__ __launch_bounds__(64) void k_agg2_lsm(const float* __restrict__ h2f,
                                                 const int* __restrict__ gdeg,
                                                 const int* __restrict__ ell,
                                                 const float* __restrict__ b,
                                                 float* __restrict__ out) {
    __shared__ int   sidx[64];
    __shared__ float swt[64];
    int v = blockIdx.x;
    int t = threadIdx.x;
    int deg = gdeg[v]; if (deg > MAXDEG) deg = MAXDEG;
    float dv = rsqrtf((float)(deg + 1));
    int s = 0; float wt = 0.f;
    if (t < deg) {
        s = ell[v * MAXDEG + t];
        wt = rsqrtf((float)(gdeg[s] + 1)) * dv;
    }
    sidx[t] = s; swt[t] = wt;
    __syncthreads();

    float acc[8];
#pragma unroll
    for (int k = 0; k < 8; k++) acc[k] = 0.f;
    acc[0] = h2f[(size_t)v * 64 + t] * (dv * dv);

    int nr = (deg + 7) & ~7;
    for (int i = 0; i < nr; i += 8) {
        int   sK[8]; float wK[8];
#pragma unroll
        for (int k = 0; k < 8; k++) { sK[k] = sidx[i + k]; wK[k] = swt[i + k]; }
#pragma unroll
        for (int k = 0; k < 8; k++)
            acc[k] += h2f[(size_t)sK[k] * 64 + t] * wK[k];
    }
    float h = ((acc[0] + acc[1]) + (acc[2] + acc[3])) +
              ((acc[4] + acc[5]) + (acc[6] + acc[7]));
    h += b[t];
    out[(size_t)v * 64 + t] = h;           // output 0: h
    float m = h;
#pragma unroll
    for (int off = 32; off >= 1; off >>= 1) m = fmaxf(m, __shfl_xor(m, off, 64));
    float e = expf(h - m);
    float ssum = e;
#pragma unroll
    for (int off = 32; off >= 1; off >>= 1) ssum += __shfl_xor(ssum, off, 64);
    out[(size_t)NN * OF + (size_t)v * 64 + t] = h - m - logf(ssum);  // output 1
}

// ---------------- launch ----------------

extern "C" void kernel_launch(void* const* d_in, const int* in_sizes, int n_in,
                              void* d_out, int out_size, void* d_ws, size_t ws_size,
                              hipStream_t stream) {
    const float* x  = (const float*)d_in[0];
    const int*   ei = (const int*)d_in[1];
    const float* W1 = (const float*)d_in[2];
    const float* b1 = (const float*)d_in[3];
    const float* W2 = (const float*)d_in[4];
    const float* b2 = (const float*)d_in[5];
    float* out = (float*)d_out;

    int E = in_sizes[1] / 2;             // 163840
    const int* src = ei;
    const int* dst = ei + E;

    char* w = (char*)d_ws;
    auto carve = [&](size_t bytes) {
        char* p = w;
        w += (bytes + 255) & ~size_t(255);
        return p;
    };
    ushort* Xb     = (ushort*)carve((size_t)NN * 512 * 2);
    ushort* h1b    = (ushort*)carve((size_t)NN * 512 * 2);
    float*  h2f    = (float*)carve((size_t)NN * 64 * 4);    // fp32 partial-sum target
    ushort* W1Tb   = (ushort*)carve((size_t)512 * 512 * 2);
    ushort* W2Tb   = (ushort*)carve((size_t)64 * 512 * 2);
    int*   gdeg    = (int*)carve((size_t)NN * 4);
    int*   ell     = (int*)carve((size_t)NN * MAXDEG * 4);  // 2.56 MB
    (void)ws_size;

    // 4 dispatches (was 5): agg1+gemm2 fused (aggregation is linear; slice-local
    // partial GEMM + fp32 atomics). Measured ~8.6 us/dispatch replay overhead.
    int fillB = (E + 255) / 256;
    k_cvt<<<CCB_H2, 256, 0, stream>>>(x, Xb, W1, W1Tb, W2, W2Tb, gdeg, h2f);
    k_gemm_ell<<<GEMM_B + fillB, 256, 0, stream>>>(Xb, W1Tb, h1b, src, dst,
                                                   gdeg, ell, E);
    k_fuse<<<FUSE_B, 256, 0, stream>>>(h1b, gdeg, ell, b1, W2Tb, h2f);
    k_agg2_lsm<<<NN, 64, 0, stream>>>(h2f, gdeg, ell, b2, out);
}

// Round 14
// 131.786 us; speedup vs baseline: 1.3286x; 1.3286x over previous
//
#include <hip/hip_runtime.h>
#include <math.h>

// Problem constants (from reference)
#define NN 10000
#define INF 512
#define HF  512
#define OF  64
#define NE  163840
#define MAXDEG 64   // P(Poisson(16.4) >= 64) ~ 7e-18/node: ELL-64 is statistically exact

typedef __attribute__((ext_vector_type(8))) short bf16x8_t;   // 8 bf16 = 4 VGPRs
typedef __attribute__((ext_vector_type(4))) float f32x4_t;    // 4 fp32 acc

__device__ inline ushort f2bf(float f) {
    unsigned u = __float_as_uint(f);
    u = (u + 0x7FFF + ((u >> 16) & 1)) >> 16;   // RNE
    return (ushort)u;
}
__device__ inline float bf2f(ushort u) {
    return __uint_as_float(((unsigned)u) << 16);
}

// global -> LDS direct DMA, 16 B/lane. LDS dest = wave-uniform base + lane*16.
#define GLL(gp, lp) __builtin_amdgcn_global_load_lds(                         \
    (const __attribute__((address_space(1))) unsigned int*)(gp),              \
    (__attribute__((address_space(3))) unsigned int*)(lp), 16, 0, 0)

// ---------------- D1: conversions + gdeg zero (grid-partitioned) ----------------
#define CCB_X  2500
#define CCB_W1 2756
#define CCB_W2 2788
#define CCB_Z  2828
__global__ __launch_bounds__(256) void k_cvt(const float* __restrict__ X,
                                             ushort* __restrict__ Xb,
                                             const float* __restrict__ W1,
                                             ushort* __restrict__ W1T,
                                             const float* __restrict__ W2,
                                             ushort* __restrict__ W2T,
                                             int* __restrict__ gdeg) {
    __shared__ float tl[32][33];
    int b = blockIdx.x, t = threadIdx.x;
    if (b < CCB_X) {
        int i = (b * 256 + t) * 2;
        const float4* Xv = (const float4*)X;
        float4 v0 = Xv[i], v1 = Xv[i + 1];
        ushort4 o0, o1;
        o0.x = f2bf(v0.x); o0.y = f2bf(v0.y); o0.z = f2bf(v0.z); o0.w = f2bf(v0.w);
        o1.x = f2bf(v1.x); o1.y = f2bf(v1.y); o1.z = f2bf(v1.z); o1.w = f2bf(v1.w);
        ((ushort4*)Xb)[i] = o0;
        ((ushort4*)Xb)[i + 1] = o1;
    } else if (b < CCB_W2) {
        const float* W; ushort* WT; int N, tile;
        if (b < CCB_W1) { W = W1; WT = W1T; N = 512; tile = b - CCB_X; }
        else            { W = W2; WT = W2T; N = 64;  tile = b - CCB_W1; }
        int k0 = (tile & 15) * 32;
        int n0 = (tile >> 4) * 32;
        int tx = t & 31, ty = t >> 5;
#pragma unroll
        for (int i = 0; i < 4; i++)
            tl[ty + i * 8][tx] = W[(size_t)(k0 + ty + i * 8) * N + n0 + tx];
        __syncthreads();
#pragma unroll
        for (int i = 0; i < 4; i++)
            WT[(size_t)(n0 + ty + i * 8) * 512 + k0 + tx] = f2bf(tl[tx][ty + i * 8]);
    } else {
        int i = (b - CCB_W2) * 256 + t;
        if (i < NN) gdeg[i] = 0;
    }
}

// ---------------- D2: MFMA GEMM1 (128x128, global_load_lds + XOR swizzle) + ELL ----
// LDS layout (unpadded): tile[row][slot][8], slot = kgroup ^ (row&7).
#define GEMM_B 316
__global__ __launch_bounds__(256) void k_gemm_ell(const ushort* __restrict__ Xb,
                                                  const ushort* __restrict__ WT,
                                                  ushort* __restrict__ Y,
                                                  const int* __restrict__ src,
                                                  const int* __restrict__ dst,
                                                  int* __restrict__ gdeg,
                                                  int* __restrict__ ell, int E) {
    __shared__ ushort As[128 * 64];   // 16 KB
    __shared__ ushort Bs[128 * 64];   // 16 KB
    int b = blockIdx.x;
    int tid = threadIdx.x;
    if (b >= GEMM_B) {
        int e = (b - GEMM_B) * 256 + tid;
        if (e < E) {
            int s = src[e], d = dst[e];
            int r = atomicAdd(&gdeg[d], 1);
            if (r < MAXDEG) ell[d * MAXDEG + r] = s;
        }
        return;
    }
    int lane = tid & 63;
    int wave = tid >> 6;
    int m = lane & 15;
    int q = lane >> 4;
    int m7 = m & 7;
    int wr = wave >> 1;
    int wc = wave & 1;
    int row0 = (b % 79) * 128;
    int col0 = (b / 79) * 128;

    int lrow = lane >> 3;
    int lg = ((lane & 7) ^ lrow) * 8;

    f32x4_t acc[4][4];
#pragma unroll
    for (int r = 0; r < 4; r++)
#pragma unroll
        for (int c = 0; c < 4; c++) acc[r][c] = (f32x4_t){0.f, 0.f, 0.f, 0.f};

    const ushort* gA0 = Xb + (size_t)(row0 + wave * 32 + lrow) * 512 + lg;
    const ushort* gB0 = WT + (size_t)(col0 + wave * 32 + lrow) * 512 + lg;
    ushort* lA0 = As + (wave * 32) * 64;
    ushort* lB0 = Bs + (wave * 32) * 64;

    for (int kb = 0; kb < 512; kb += 64) {
#pragma unroll
        for (int j = 0; j < 4; j++) {
            GLL(gA0 + kb + j * 8 * 512, lA0 + j * 8 * 64);
            GLL(gB0 + kb + j * 8 * 512, lB0 + j * 8 * 64);
        }
        __syncthreads();
#pragma unroll
        for (int kc = 0; kc < 2; kc++) {
            bf16x8_t a[4], bb[4];
            int slot = ((kc * 4 + q) ^ m7) * 8;
#pragma unroll
            for (int r = 0; r < 4; r++)
                a[r] = *(const bf16x8_t*)(As + (wr * 64 + r * 16 + m) * 64 + slot);
#pragma unroll
            for (int c = 0; c < 4; c++)
                bb[c] = *(const bf16x8_t*)(Bs + (wc * 64 + c * 16 + m) * 64 + slot);
#pragma unroll
            for (int r = 0; r < 4; r++)
#pragma unroll
                for (int c = 0; c < 4; c++)
                    acc[r][c] = __builtin_amdgcn_mfma_f32_16x16x32_bf16(a[r], bb[c], acc[r][c], 0, 0, 0);
        }
        __syncthreads();
    }
#pragma unroll
    for (int r = 0; r < 4; r++) {
#pragma unroll
        for (int c = 0; c < 4; c++) {
#pragma unroll
            for (int reg = 0; reg < 4; reg++) {
                int row = row0 + wr * 64 + r * 16 + q * 4 + reg;
                int col = col0 + wc * 64 + c * 16 + m;
                if (row < NN) Y[(size_t)row * 512 + col] = f2bf(acc[r][c][reg]);
            }
        }
    }
}

// ---------------- MFMA GEMM2 (64x64, global_load_lds + XOR swizzle) ----------------
__global__ __launch_bounds__(256) void k_gemm64_mfma(const ushort* __restrict__ Ab,
                                                     const ushort* __restrict__ W2T,
                                                     ushort* __restrict__ Y) {
    __shared__ ushort As[64 * 64];    // 8 KB
    __shared__ ushort Bs[64 * 64];    // 8 KB
    int tid = threadIdx.x;
    int lane = tid & 63;
    int wave = tid >> 6;
    int m = lane & 15;
    int q = lane >> 4;
    int m7 = m & 7;
    int row0 = blockIdx.x * 64;

    int lrow = lane >> 3;
    int lg = ((lane & 7) ^ lrow) * 8;

    f32x4_t acc[4];
#pragma unroll
    for (int c = 0; c < 4; c++) acc[c] = (f32x4_t){0.f, 0.f, 0.f, 0.f};

    const ushort* gA0 = Ab + (size_t)(row0 + wave * 16 + lrow) * 512 + lg;
    const ushort* gB0 = W2T + (size_t)(wave * 16 + lrow) * 512 + lg;
    ushort* lA0 = As + (wave * 16) * 64;
    ushort* lB0 = Bs + (wave * 16) * 64;

    for (int kb = 0; kb < 512; kb += 64) {
#pragma unroll
        for (int j = 0; j < 2; j++) {
            GLL(gA0 + kb + j * 8 * 512, lA0 + j * 8 * 64);
            GLL(gB0 + kb + j * 8 * 512, lB0 + j * 8 * 64);
        }
        __syncthreads();
#pragma unroll
        for (int kc = 0; kc < 2; kc++) {
            int slot = ((kc * 4 + q) ^ m7) * 8;
            bf16x8_t a = *(const bf16x8_t*)(As + (wave * 16 + m) * 64 + slot);
#pragma unroll
            for (int c = 0; c < 4; c++) {
                bf16x8_t bfr = *(const bf16x8_t*)(Bs + (c * 16 + m) * 64 + slot);
                acc[c] = __builtin_amdgcn_mfma_f32_16x16x32_bf16(a, bfr, acc[c], 0, 0, 0);
            }
        }
        __syncthreads();
    }
#pragma unroll
    for (int c = 0; c < 4; c++) {
#pragma unroll
        for (int reg = 0; reg < 4; reg++) {
            int row = row0 + wave * 16 + q * 4 + reg;
            int col = c * 16 + m;
            if (row < NN) Y[(size_t)row * 64 + col] = f2bf(acc[c][reg]);
        }
    }
}

// ---------------- aggregate layer 1: ELL, 4 slices x 128 feats, ushort2 gathers ------
// slice-0 blocks also persist the per-edge weights (wts) for reuse by agg2.
__global__ __launch_bounds__(64) void k_agg1(const ushort* __restrict__ h1b,
                                             const int* __restrict__ gdeg,
                                             const int* __restrict__ ell,
                                             const float* __restrict__ b,
                                             ushort* __restrict__ a1b,
                                             float* __restrict__ wts) {
    __shared__ int   sidx[64];
    __shared__ float swt[64];
    int bid = blockIdx.x;
    int slice = bid & 3;
    int v = bid >> 2;
    int t = threadIdx.x;
    int fb = slice * 128 + t * 2;
    int deg = gdeg[v]; if (deg > MAXDEG) deg = MAXDEG;
    float dv = rsqrtf((float)(deg + 1));
    int s = 0; float wt = 0.f;
    if (t < deg) {
        s = ell[v * MAXDEG + t];
        wt = rsqrtf((float)(gdeg[s] + 1)) * dv;
    }
    sidx[t] = s; swt[t] = wt;
    if (slice == 0) wts[v * MAXDEG + t] = wt;   // persist for agg2 (0 for t>=deg)
    __syncthreads();

    float ax[8], ay[8];
#pragma unroll
    for (int k = 0; k < 8; k++) { ax[k] = 0.f; ay[k] = 0.f; }
    {   // self-loop
        ushort2 u = *(const ushort2*)(h1b + (size_t)v * 512 + fb);
        float dv2 = dv * dv;
        ax[0] = bf2f(u.x) * dv2;
        ay[0] = bf2f(u.y) * dv2;
    }
    int nr = (deg + 7) & ~7;                 // extras have w=0, idx=0 (safe)
    for (int i = 0; i < nr; i += 8) {
        int   sK[8]; float wK[8];
#pragma unroll
        for (int k = 0; k < 8; k++) { sK[k] = sidx[i + k]; wK[k] = swt[i + k]; }
#pragma unroll
        for (int k = 0; k < 8; k++) {
            ushort2 u = *(const ushort2*)(h1b + (size_t)sK[k] * 512 + fb);
            ax[k] += bf2f(u.x) * wK[k];
            ay[k] += bf2f(u.y) * wK[k];
        }
    }
    float tx = ((ax[0] + ax[1]) + (ax[2] + ax[3])) + ((ax[4] + ax[5]) + (ax[6] + ax[7]));
    float ty = ((ay[0] + ay[1]) + (ay[2] + ay[3])) + ((ay[4] + ay[5]) + (ay[6] + ay[7]));
    tx += b[fb];
    ty += b[fb + 1];
    ushort2 o;
    o.x = f2bf(tx > 0.f ? tx : 0.f);
    o.y = f2bf(ty > 0.f ? ty : 0.f);
    *(ushort2*)(a1b + (size_t)v * 512 + fb) = o;
}

// ---------------- aggregate layer 2 + bias + log_softmax (ELL + precomputed wts) ----
// R13 crash fix: ell slots >= deg are UNINITIALIZED (0xAA poison). The coalesced
// loads are in-bounds, but the INDEX must be clamped before any gather uses it —
// w=0 does not guard the load address.
__global__ __launch_bounds__(64) void k_agg2_lsm(const ushort* __restrict__ h2b,
                                                 const int* __restrict__ gdeg,
                                                 const int* __restrict__ ell,
                                                 const float* __restrict__ wts,
                                                 const float* __restrict__ b,
                                                 float* __restrict__ out) {
    __shared__ int   sidx[64];
    __shared__ float swt[64];
    int v = blockIdx.x;
    int t = threadIdx.x;
    int deg = gdeg[v]; if (deg > MAXDEG) deg = MAXDEG;
    float dv = rsqrtf((float)(deg + 1));
    int   e_ = ell[v * MAXDEG + t];            // coalesced, in-bounds
    float w_ = wts[v * MAXDEG + t];            // coalesced, 0 for t>=deg
    sidx[t] = (t < deg) ? e_ : 0;              // clamp index: poison never dereferenced
    swt[t]  = (t < deg) ? w_ : 0.f;
    __syncthreads();

    float acc[8];
#pragma unroll
    for (int k = 0; k < 8; k++) acc[k] = 0.f;
    acc[0] = bf2f(h2b[(size_t)v * 64 + t]) * (dv * dv);

    int nr = (deg + 7) & ~7;
    for (int i = 0; i < nr; i += 8) {
        int   sK[8]; float wK[8];
#pragma unroll
        for (int k = 0; k < 8; k++) { sK[k] = sidx[i + k]; wK[k] = swt[i + k]; }
#pragma unroll
        for (int k = 0; k < 8; k++)
            acc[k] += bf2f(h2b[(size_t)sK[k] * 64 + t]) * wK[k];
    }
    float h = ((acc[0] + acc[1]) + (acc[2] + acc[3])) +
              ((acc[4] + acc[5]) + (acc[6] + acc[7]));
    h += b[t];
    out[(size_t)v * 64 + t] = h;           // output 0: h
    float m = h;
#pragma unroll
    for (int off = 32; off >= 1; off >>= 1) m = fmaxf(m, __shfl_xor(m, off, 64));
    float e = expf(h - m);
    float ssum = e;
#pragma unroll
    for (int off = 32; off >= 1; off >>= 1) ssum += __shfl_xor(ssum, off, 64);
    out[(size_t)NN * OF + (size_t)v * 64 + t] = h - m - logf(ssum);  // output 1
}

// ---------------- launch ----------------

extern "C" void kernel_launch(void* const* d_in, const int* in_sizes, int n_in,
                              void* d_out, int out_size, void* d_ws, size_t ws_size,
                              hipStream_t stream) {
    const float* x  = (const float*)d_in[0];
    const int*   ei = (const int*)d_in[1];
    const float* W1 = (const float*)d_in[2];
    const float* b1 = (const float*)d_in[3];
    const float* W2 = (const float*)d_in[4];
    const float* b2 = (const float*)d_in[5];
    float* out = (float*)d_out;

    int E = in_sizes[1] / 2;             // 163840
    const int* src = ei;
    const int* dst = ei + E;

    char* w = (char*)d_ws;
    auto carve = [&](size_t bytes) {
        char* p = w;
        w += (bytes + 255) & ~size_t(255);
        return p;
    };
    ushort* Xb     = (ushort*)carve((size_t)NN * 512 * 2);
    ushort* h1b    = (ushort*)carve((size_t)NN * 512 * 2);
    ushort* a1b    = (ushort*)carve((size_t)NN * 512 * 2);
    ushort* h2b    = (ushort*)carve((size_t)NN * 64 * 2);
    ushort* W1Tb   = (ushort*)carve((size_t)512 * 512 * 2);
    ushort* W2Tb   = (ushort*)carve((size_t)64 * 512 * 2);
    int*   gdeg    = (int*)carve((size_t)NN * 4);
    int*   ell     = (int*)carve((size_t)NN * MAXDEG * 4);  // 2.56 MB
    float* wts     = (float*)carve((size_t)NN * MAXDEG * 4); // 2.56 MB
    (void)ws_size;

    // 5 dispatches. R12 lesson: do NOT fuse the latency-bound gather phase into a
    // low-block-count kernel. R6 lesson: no cooperative launch.
    int fillB = (E + 255) / 256;
    k_cvt<<<CCB_Z, 256, 0, stream>>>(x, Xb, W1, W1Tb, W2, W2Tb, gdeg);
    k_gemm_ell<<<GEMM_B + fillB, 256, 0, stream>>>(Xb, W1Tb, h1b, src, dst,
                                                   gdeg, ell, E);
    k_agg1<<<NN * 4, 64, 0, stream>>>(h1b, gdeg, ell, b1, a1b, wts);
    k_gemm64_mfma<<<(NN + 63) / 64, 256, 0, stream>>>(a1b, W2Tb, h2b);
    k_agg2_lsm<<<NN, 64, 0, stream>>>(h2b, gdeg, ell, wts, b2, out);
}

// Round 15
// 127.249 us; speedup vs baseline: 1.3759x; 1.0357x over previous
//
#include <hip/hip_runtime.h>
#include <math.h>

// Problem constants (from reference)
#define NN 10000
#define INF 512
#define HF  512
#define OF  64
#define NE  163840
#define MAXDEG 64   // P(Poisson(16.4) >= 64) ~ 7e-18/node: ELL-64 is statistically exact

typedef __attribute__((ext_vector_type(8))) short bf16x8_t;   // 8 bf16 = 4 VGPRs
typedef __attribute__((ext_vector_type(4))) float f32x4_t;    // 4 fp32 acc

__device__ inline ushort f2bf(float f) {
    unsigned u = __float_as_uint(f);
    u = (u + 0x7FFF + ((u >> 16) & 1)) >> 16;   // RNE
    return (ushort)u;
}
__device__ inline float bf2f(ushort u) {
    return __uint_as_float(((unsigned)u) << 16);
}

// global -> LDS direct DMA, 16 B/lane. LDS dest = wave-uniform base + lane*16.
#define GLL(gp, lp) __builtin_amdgcn_global_load_lds(                         \
    (const __attribute__((address_space(1))) unsigned int*)(gp),              \
    (__attribute__((address_space(3))) unsigned int*)(lp), 16, 0, 0)

// ---------------- D1: conversions + gdeg zero (grid-partitioned) ----------------
#define CCB_X  2500
#define CCB_W1 2756
#define CCB_W2 2788
#define CCB_Z  2828
__global__ __launch_bounds__(256) void k_cvt(const float* __restrict__ X,
                                             ushort* __restrict__ Xb,
                                             const float* __restrict__ W1,
                                             ushort* __restrict__ W1T,
                                             const float* __restrict__ W2,
                                             ushort* __restrict__ W2T,
                                             int* __restrict__ gdeg) {
    __shared__ float tl[32][33];
    int b = blockIdx.x, t = threadIdx.x;
    if (b < CCB_X) {
        int i = (b * 256 + t) * 2;
        const float4* Xv = (const float4*)X;
        float4 v0 = Xv[i], v1 = Xv[i + 1];
        ushort4 o0, o1;
        o0.x = f2bf(v0.x); o0.y = f2bf(v0.y); o0.z = f2bf(v0.z); o0.w = f2bf(v0.w);
        o1.x = f2bf(v1.x); o1.y = f2bf(v1.y); o1.z = f2bf(v1.z); o1.w = f2bf(v1.w);
        ((ushort4*)Xb)[i] = o0;
        ((ushort4*)Xb)[i + 1] = o1;
    } else if (b < CCB_W2) {
        const float* W; ushort* WT; int N, tile;
        if (b < CCB_W1) { W = W1; WT = W1T; N = 512; tile = b - CCB_X; }
        else            { W = W2; WT = W2T; N = 64;  tile = b - CCB_W1; }
        int k0 = (tile & 15) * 32;
        int n0 = (tile >> 4) * 32;
        int tx = t & 31, ty = t >> 5;
#pragma unroll
        for (int i = 0; i < 4; i++)
            tl[ty + i * 8][tx] = W[(size_t)(k0 + ty + i * 8) * N + n0 + tx];
        __syncthreads();
#pragma unroll
        for (int i = 0; i < 4; i++)
            WT[(size_t)(n0 + ty + i * 8) * 512 + k0 + tx] = f2bf(tl[tx][ty + i * 8]);
    } else {
        int i = (b - CCB_W2) * 256 + t;
        if (i < NN) gdeg[i] = 0;
    }
}

// ---------------- D2: MFMA GEMM1 (128x128, BK=128, GLL + XOR swizzle) + ELL --------
// BK=128: 4 barriers instead of 8 — at ~1.2 blocks/CU the vmcnt(0) barrier drain
// is un-hidden, so halving barrier count halves the stall count (m132's BK=128
// regression was an occupancy cliff at 3 blocks/CU; irrelevant here).
// LDS row = 128 k = 16 groups x 16B; slot = g ^ (row&15); bank sets stay balanced.
#define GEMM_B 316
__global__ __launch_bounds__(256) void k_gemm_ell(const ushort* __restrict__ Xb,
                                                  const ushort* __restrict__ WT,
                                                  ushort* __restrict__ Y,
                                                  const int* __restrict__ src,
                                                  const int* __restrict__ dst,
                                                  int* __restrict__ gdeg,
                                                  int* __restrict__ ell, int E) {
    __shared__ ushort As[128 * 128];   // 32 KB
    __shared__ ushort Bs[128 * 128];   // 32 KB
    int b = blockIdx.x;
    int tid = threadIdx.x;
    if (b >= GEMM_B) {
        int e = (b - GEMM_B) * 256 + tid;
        if (e < E) {
            int s = src[e], d = dst[e];
            int r = atomicAdd(&gdeg[d], 1);
            if (r < MAXDEG) ell[d * MAXDEG + r] = s;
        }
        return;
    }
    int lane = tid & 63;
    int wave = tid >> 6;
    int m = lane & 15;
    int q = lane >> 4;
    int wr = wave >> 1;
    int wc = wave & 1;
    int row0 = (b % 79) * 128;
    int col0 = (b / 79) * 128;

    // staging lane map: 1 issue = 1 KB = 4 rows x 256 B; lrow = lane>>4, chunk p = lane&15.
    // LDS slot s = p; global k-group g = p ^ (row&15); row&15 = (j*4+lrow)&15 -> 4 patterns.
    int lrow = lane >> 4;
    int p = lane & 15;
    int koff[4];
#pragma unroll
    for (int jm = 0; jm < 4; jm++) koff[jm] = (p ^ ((jm * 4 + lrow) & 15)) * 8;

    f32x4_t acc[4][4];
#pragma unroll
    for (int r = 0; r < 4; r++)
#pragma unroll
        for (int c = 0; c < 4; c++) acc[r][c] = (f32x4_t){0.f, 0.f, 0.f, 0.f};

    for (int kb = 0; kb < 512; kb += 128) {
#pragma unroll
        for (int j = 0; j < 8; j++) {
            int rloc = wave * 32 + j * 4;
            GLL(Xb + (size_t)(row0 + rloc + lrow) * 512 + kb + koff[j & 3],
                As + rloc * 128);
            GLL(WT + (size_t)(col0 + rloc + lrow) * 512 + kb + koff[j & 3],
                Bs + rloc * 128);
        }
        __syncthreads();
#pragma unroll
        for (int kc = 0; kc < 4; kc++) {
            bf16x8_t a[4], bb[4];
            int slot = ((kc * 4 + q) ^ m) * 8;
#pragma unroll
            for (int r = 0; r < 4; r++)
                a[r] = *(const bf16x8_t*)(As + (wr * 64 + r * 16 + m) * 128 + slot);
#pragma unroll
            for (int c = 0; c < 4; c++)
                bb[c] = *(const bf16x8_t*)(Bs + (wc * 64 + c * 16 + m) * 128 + slot);
#pragma unroll
            for (int r = 0; r < 4; r++)
#pragma unroll
                for (int c = 0; c < 4; c++)
                    acc[r][c] = __builtin_amdgcn_mfma_f32_16x16x32_bf16(a[r], bb[c], acc[r][c], 0, 0, 0);
        }
        __syncthreads();
    }
#pragma unroll
    for (int r = 0; r < 4; r++) {
#pragma unroll
        for (int c = 0; c < 4; c++) {
#pragma unroll
            for (int reg = 0; reg < 4; reg++) {
                int row = row0 + wr * 64 + r * 16 + q * 4 + reg;
                int col = col0 + wc * 64 + c * 16 + m;
                if (row < NN) Y[(size_t)row * 512 + col] = f2bf(acc[r][c][reg]);
            }
        }
    }
}

// ---------------- MFMA GEMM2 (64x64, BK=128, GLL + XOR swizzle) ----------------
__global__ __launch_bounds__(256) void k_gemm64_mfma(const ushort* __restrict__ Ab,
                                                     const ushort* __restrict__ W2T,
                                                     ushort* __restrict__ Y) {
    __shared__ ushort As[64 * 128];    // 16 KB
    __shared__ ushort Bs[64 * 128];    // 16 KB
    int tid = threadIdx.x;
    int lane = tid & 63;
    int wave = tid >> 6;
    int m = lane & 15;
    int q = lane >> 4;
    int row0 = blockIdx.x * 64;

    int lrow = lane >> 4;
    int p = lane & 15;
    int koff[4];
#pragma unroll
    for (int jm = 0; jm < 4; jm++) koff[jm] = (p ^ ((jm * 4 + lrow) & 15)) * 8;

    f32x4_t acc[4];
#pragma unroll
    for (int c = 0; c < 4; c++) acc[c] = (f32x4_t){0.f, 0.f, 0.f, 0.f};

    for (int kb = 0; kb < 512; kb += 128) {
#pragma unroll
        for (int j = 0; j < 4; j++) {
            int rloc = wave * 16 + j * 4;
            GLL(Ab + (size_t)(row0 + rloc + lrow) * 512 + kb + koff[j],
                As + rloc * 128);
            GLL(W2T + (size_t)(rloc + lrow) * 512 + kb + koff[j],
                Bs + rloc * 128);
        }
        __syncthreads();
#pragma unroll
        for (int kc = 0; kc < 4; kc++) {
            int slot = ((kc * 4 + q) ^ m) * 8;
            bf16x8_t a = *(const bf16x8_t*)(As + (wave * 16 + m) * 128 + slot);
#pragma unroll
            for (int c = 0; c < 4; c++) {
                bf16x8_t bfr = *(const bf16x8_t*)(Bs + (c * 16 + m) * 128 + slot);
                acc[c] = __builtin_amdgcn_mfma_f32_16x16x32_bf16(a, bfr, acc[c], 0, 0, 0);
            }
        }
        __syncthreads();
    }
#pragma unroll
    for (int c = 0; c < 4; c++) {
#pragma unroll
        for (int reg = 0; reg < 4; reg++) {
            int row = row0 + wave * 16 + q * 4 + reg;
            int col = c * 16 + m;
            if (row < NN) Y[(size_t)row * 64 + col] = f2bf(acc[c][reg]);
        }
    }
}

// ---------------- aggregate layer 1: ELL, 4 slices x 128 feats, ushort2 gathers ------
// slice-0 blocks also persist the per-edge weights (wts) for reuse by agg2.
__global__ __launch_bounds__(64) void k_agg1(const ushort* __restrict__ h1b,
                                             const int* __restrict__ gdeg,
                                             const int* __restrict__ ell,
                                             const float* __restrict__ b,
                                             ushort* __restrict__ a1b,
                                             float* __restrict__ wts) {
    __shared__ int   sidx[64];
    __shared__ float swt[64];
    int bid = blockIdx.x;
    int slice = bid & 3;
    int v = bid >> 2;
    int t = threadIdx.x;
    int fb = slice * 128 + t * 2;
    int deg = gdeg[v]; if (deg > MAXDEG) deg = MAXDEG;
    float dv = rsqrtf((float)(deg + 1));
    int s = 0; float wt = 0.f;
    if (t < deg) {
        s = ell[v * MAXDEG + t];
        wt = rsqrtf((float)(gdeg[s] + 1)) * dv;
    }
    sidx[t] = s; swt[t] = wt;
    if (slice == 0) wts[v * MAXDEG + t] = wt;   // persist for agg2 (0 for t>=deg)
    __syncthreads();

    float ax[8], ay[8];
#pragma unroll
    for (int k = 0; k < 8; k++) { ax[k] = 0.f; ay[k] = 0.f; }
    {   // self-loop
        ushort2 u = *(const ushort2*)(h1b + (size_t)v * 512 + fb);
        float dv2 = dv * dv;
        ax[0] = bf2f(u.x) * dv2;
        ay[0] = bf2f(u.y) * dv2;
    }
    int nr = (deg + 7) & ~7;                 // extras have w=0, idx=0 (safe)
    for (int i = 0; i < nr; i += 8) {
        int   sK[8]; float wK[8];
#pragma unroll
        for (int k = 0; k < 8; k++) { sK[k] = sidx[i + k]; wK[k] = swt[i + k]; }
#pragma unroll
        for (int k = 0; k < 8; k++) {
            ushort2 u = *(const ushort2*)(h1b + (size_t)sK[k] * 512 + fb);
            ax[k] += bf2f(u.x) * wK[k];
            ay[k] += bf2f(u.y) * wK[k];
        }
    }
    float tx = ((ax[0] + ax[1]) + (ax[2] + ax[3])) + ((ax[4] + ax[5]) + (ax[6] + ax[7]));
    float ty = ((ay[0] + ay[1]) + (ay[2] + ay[3])) + ((ay[4] + ay[5]) + (ay[6] + ay[7]));
    tx += b[fb];
    ty += b[fb + 1];
    ushort2 o;
    o.x = f2bf(tx > 0.f ? tx : 0.f);
    o.y = f2bf(ty > 0.f ? ty : 0.f);
    *(ushort2*)(a1b + (size_t)v * 512 + fb) = o;
}

// ---------------- aggregate layer 2 + bias + log_softmax (ELL + precomputed wts) ----
// R13 lesson: ell slots >= deg are uninitialized poison — clamp the INDEX before
// any gather uses it; w=0 does not guard the load address.
__global__ __launch_bounds__(64) void k_agg2_lsm(const ushort* __restrict__ h2b,
                                                 const int* __restrict__ gdeg,
                                                 const int* __restrict__ ell,
                                                 const float* __restrict__ wts,
                                                 const float* __restrict__ b,
                                                 float* __restrict__ out) {
    __shared__ int   sidx[64];
    __shared__ float swt[64];
    int v = blockIdx.x;
    int t = threadIdx.x;
    int deg = gdeg[v]; if (deg > MAXDEG) deg = MAXDEG;
    float dv = rsqrtf((float)(deg + 1));
    int   e_ = ell[v * MAXDEG + t];            // coalesced, in-bounds
    float w_ = wts[v * MAXDEG + t];            // coalesced, 0 for t>=deg
    sidx[t] = (t < deg) ? e_ : 0;              // clamp index: poison never dereferenced
    swt[t]  = (t < deg) ? w_ : 0.f;
    __syncthreads();

    float acc[8];
#pragma unroll
    for (int k = 0; k < 8; k++) acc[k] = 0.f;
    acc[0] = bf2f(h2b[(size_t)v * 64 + t]) * (dv * dv);

    int nr = (deg + 7) & ~7;
    for (int i = 0; i < nr; i += 8) {
        int   sK[8]; float wK[8];
#pragma unroll
        for (int k = 0; k < 8; k++) { sK[k] = sidx[i + k]; wK[k] = swt[i + k]; }
#pragma unroll
        for (int k = 0; k < 8; k++)
            acc[k] += bf2f(h2b[(size_t)sK[k] * 64 + t]) * wK[k];
    }
    float h = ((acc[0] + acc[1]) + (acc[2] + acc[3])) +
              ((acc[4] + acc[5]) + (acc[6] + acc[7]));
    h += b[t];
    out[(size_t)v * 64 + t] = h;           // output 0: h
    float m = h;
#pragma unroll
    for (int off = 32; off >= 1; off >>= 1) m = fmaxf(m, __shfl_xor(m, off, 64));
    float e = expf(h - m);
    float ssum = e;
#pragma unroll
    for (int off = 32; off >= 1; off >>= 1) ssum += __shfl_xor(ssum, off, 64);
    out[(size_t)NN * OF + (size_t)v * 64 + t] = h - m - logf(ssum);  // output 1
}

// ---------------- launch ----------------

extern "C" void kernel_launch(void* const* d_in, const int* in_sizes, int n_in,
                              void* d_out, int out_size, void* d_ws, size_t ws_size,
                              hipStream_t stream) {
    const float* x  = (const float*)d_in[0];
    const int*   ei = (const int*)d_in[1];
    const float* W1 = (const float*)d_in[2];
    const float* b1 = (const float*)d_in[3];
    const float* W2 = (const float*)d_in[4];
    const float* b2 = (const float*)d_in[5];
    float* out = (float*)d_out;

    int E = in_sizes[1] / 2;             // 163840
    const int* src = ei;
    const int* dst = ei + E;

    char* w = (char*)d_ws;
    auto carve = [&](size_t bytes) {
        char* p = w;
        w += (bytes + 255) & ~size_t(255);
        return p;
    };
    ushort* Xb     = (ushort*)carve((size_t)NN * 512 * 2);
    ushort* h1b    = (ushort*)carve((size_t)NN * 512 * 2);
    ushort* a1b    = (ushort*)carve((size_t)NN * 512 * 2);
    ushort* h2b    = (ushort*)carve((size_t)NN * 64 * 2);
    ushort* W1Tb   = (ushort*)carve((size_t)512 * 512 * 2);
    ushort* W2Tb   = (ushort*)carve((size_t)64 * 512 * 2);
    int*   gdeg    = (int*)carve((size_t)NN * 4);
    int*   ell     = (int*)carve((size_t)NN * MAXDEG * 4);  // 2.56 MB
    float* wts     = (float*)carve((size_t)NN * MAXDEG * 4); // 2.56 MB
    (void)ws_size;

    // 5 dispatches. R12 lesson: do NOT fuse the latency-bound gather phase into a
    // low-block-count kernel. R6 lesson: no cooperative launch.
    int fillB = (E + 255) / 256;
    k_cvt<<<CCB_Z, 256, 0, stream>>>(x, Xb, W1, W1Tb, W2, W2Tb, gdeg);
    k_gemm_ell<<<GEMM_B + fillB, 256, 0, stream>>>(Xb, W1Tb, h1b, src, dst,
                                                   gdeg, ell, E);
    k_agg1<<<NN * 4, 64, 0, stream>>>(h1b, gdeg, ell, b1, a1b, wts);
    k_gemm64_mfma<<<(NN + 63) / 64, 256, 0, stream>>>(a1b, W2Tb, h2b);
    k_agg2_lsm<<<NN, 64, 0, stream>>>(h2b, gdeg, ell, wts, b2, out);
}